// Round 17
// baseline (237.866 us; speedup 1.0000x reference)
//
#include <hip/hip_runtime.h>
#include <stdint.h>

// Super-ko filter for Go. Staging: bool inputs are int32 0/1 (verified r7).
//  0 legal_mask (B,19,19) i32 | 1 capture (B,361,361) i32 | 2 player (B,) i32
//  3 zpos (361,3) i32 | 4 chash (B,) i32 | 5 hist (B,3610) i32
//  6 mcount (B,) i32 | 7 logits (B,19,19) f32 -> out (B,19,19) f32
//
// r12 post-mortem: every "sparse decode + LDS atomicXor" variant saturates at
// ~2 TB/s regardless of occupancy/spill fixes — the divergent decode between
// load batches is the structural bottleneck (waves almost never skip; exec-
// mask branch + DS-atomic machinery throttles issue). This version: branchless
// wave-per-row XOR reduction. Lane l covers j=l+64s; acc ^= mask?D[s]:0
// (cmp+cndmask+xor, unconditional); 6-step shfl_xor butterfly; lane 0 writes
// capx[b][i]. No LDS, no atomics, no branches in the hot loop.

#define GO_B   256
#define GO_N2  361
#define GO_M   3610
#define TBL    1024
#define BTHR   512

__global__ __launch_bounds__(256)
void scan_kernel(const int* __restrict__ cap,
                 const int* __restrict__ player,
                 const int* __restrict__ zpos,
                 uint32_t*  __restrict__ capx_out)   // [GO_B][GO_N2]
{
    const int b    = blockIdx.x >> 2;          // batch
    const int g    = blockIdx.x & 3;           // row-group
    const int wid  = g * 4 + (threadIdx.x >> 6);  // 0..15: wave id within batch
    const int lane = threadIdx.x & 63;
    const int p    = player[b];

    // Preload D[j] for this lane's 6 column slots j = lane + 64s (same for
    // every row of this batch). j<361 guard -> 0 contribution.
    uint32_t D[6];
    #pragma unroll
    for (int s = 0; s < 6; ++s) {
        int j = lane + 64 * s;
        D[s] = (j < GO_N2)
             ? ((uint32_t)zpos[j * 3 + 0] ^ (uint32_t)zpos[j * 3 + 2 - p])
             : 0u;
    }

    const int* __restrict__ base_b = cap + (size_t)b * GO_N2 * GO_N2;

    // Rows r ≡ wid (mod 16); paired (i, i+16) per iteration for MLP.
    for (int i = wid; i < GO_N2; i += 32) {
        const int  iB   = i + 16;
        const bool hasB = (iB < GO_N2);
        const int* __restrict__ rowA = base_b + (size_t)i  * GO_N2;
        const int* __restrict__ rowB = base_b + (size_t)iB * GO_N2;

        uint32_t a0, a1, a2, a3, a4, a5;        // named regs: no dyn indexing
        uint32_t b0, b1, b2, b3, b4, b5;
        a0 = (uint32_t)rowA[lane];
        a1 = (uint32_t)rowA[lane + 64];
        a2 = (uint32_t)rowA[lane + 128];
        a3 = (uint32_t)rowA[lane + 192];
        a4 = (uint32_t)rowA[lane + 256];
        a5 = (lane + 320 < GO_N2) ? (uint32_t)rowA[lane + 320] : 0u;
        b0 = hasB ? (uint32_t)rowB[lane]       : 0u;
        b1 = hasB ? (uint32_t)rowB[lane + 64]  : 0u;
        b2 = hasB ? (uint32_t)rowB[lane + 128] : 0u;
        b3 = hasB ? (uint32_t)rowB[lane + 192] : 0u;
        b4 = hasB ? (uint32_t)rowB[lane + 256] : 0u;
        b5 = (hasB && lane + 320 < GO_N2) ? (uint32_t)rowB[lane + 320] : 0u;

        uint32_t accA = (a0 ? D[0] : 0u) ^ (a1 ? D[1] : 0u) ^ (a2 ? D[2] : 0u)
                      ^ (a3 ? D[3] : 0u) ^ (a4 ? D[4] : 0u) ^ (a5 ? D[5] : 0u);
        uint32_t accB = (b0 ? D[0] : 0u) ^ (b1 ? D[1] : 0u) ^ (b2 ? D[2] : 0u)
                      ^ (b3 ? D[3] : 0u) ^ (b4 ? D[4] : 0u) ^ (b5 ? D[5] : 0u);

        // 64-lane XOR butterfly
        #pragma unroll
        for (int off = 32; off >= 1; off >>= 1) {
            accA ^= __shfl_xor(accA, off, 64);
            accB ^= __shfl_xor(accB, off, 64);
        }
        if (lane == 0) {
            capx_out[(size_t)b * GO_N2 + i] = accA;
            if (hasB) capx_out[(size_t)b * GO_N2 + iB] = accB;
        }
    }
}

__global__ __launch_bounds__(BTHR)
void finalize_kernel(const int*      __restrict__ legal,
                     const int*      __restrict__ player,
                     const int*      __restrict__ zpos,
                     const int*      __restrict__ chash,
                     const int*      __restrict__ hist,
                     const int*      __restrict__ mcount,
                     const float*    __restrict__ logits,
                     const uint32_t* __restrict__ capx,
                     float*          __restrict__ out)
{
    __shared__ uint32_t thash[TBL];
    __shared__ int      tidx[TBL];
    __shared__ uint8_t  rep[GO_N2];
    __shared__ uint8_t  leg[GO_N2];

    const int b   = blockIdx.x;
    const int tid = threadIdx.x;
    const int p   = player[b];
    const uint32_t ch = (uint32_t)chash[b];

    for (int s = tid; s < TBL; s += BTHR) tidx[s] = -1;
    for (int i = tid; i < GO_N2; i += BTHR) {
        rep[i] = 0u;
        leg[i] = legal[(size_t)b * GO_N2 + i] != 0;
    }
    __syncthreads();

    for (int i = tid; i < GO_N2; i += BTHR) {
        uint32_t z0 = (uint32_t)zpos[i * 3 + 0];
        uint32_t zp = (uint32_t)zpos[i * 3 + 1 + p];
        uint32_t nh = ch ^ (z0 ^ zp) ^ capx[(size_t)b * GO_N2 + i];
        if (leg[i]) {
            uint32_t s = nh & (TBL - 1);
            while (true) {
                int prev = atomicCAS(&tidx[s], -1, i);
                if (prev == -1) { thash[s] = nh; break; }
                s = (s + 1) & (TBL - 1);
            }
        }
    }
    __syncthreads();

    const int mc = mcount[b];
    for (int m = tid; m < mc; m += BTHR) {
        uint32_t h = (uint32_t)hist[(size_t)b * GO_M + m];
        uint32_t s = h & (TBL - 1);
        while (tidx[s] != -1) {
            if (thash[s] == h) rep[tidx[s]] = 1u;
            s = (s + 1) & (TBL - 1);
        }
    }
    __syncthreads();

    for (int i = tid; i < GO_N2; i += BTHR) {
        bool keep = leg[i] && !rep[i];
        out[(size_t)b * GO_N2 + i] =
            keep ? logits[(size_t)b * GO_N2 + i] : -1.0e9f;
    }
}

extern "C" void kernel_launch(void* const* d_in, const int* in_sizes, int n_in,
                              void* d_out, int out_size, void* d_ws, size_t ws_size,
                              hipStream_t stream) {
    const int*   legal  = (const int*)d_in[0];
    const int*   cap    = (const int*)d_in[1];
    const int*   player = (const int*)d_in[2];
    const int*   zpos   = (const int*)d_in[3];
    const int*   chash  = (const int*)d_in[4];
    const int*   hist   = (const int*)d_in[5];
    const int*   mcount = (const int*)d_in[6];
    const float* logits = (const float*)d_in[7];
    float*       outp   = (float*)d_out;
    uint32_t*    capx   = (uint32_t*)d_ws;   // 256*361*4 B = 370 KB

    scan_kernel<<<GO_B * 4, 256, 0, stream>>>(cap, player, zpos, capx);
    finalize_kernel<<<GO_B, BTHR, 0, stream>>>(legal, player, zpos, chash,
                                               hist, mcount, logits, capx, outp);
}

// Round 18
// 232.682 us; speedup vs baseline: 1.0223x; 1.0223x over previous
//
#include <hip/hip_runtime.h>
#include <stdint.h>

// Super-ko filter for Go. Staging: bool inputs are int32 0/1 (verified r7).
// r17 post-mortem: branchless butterfly scan ≈ same ~2 TB/s plateau. This
// version: LDS-staged transpose-reduce. 8 blocks/batch (disjoint row ranges),
// 2048 blocks x 256 thr, 32 waves/CU. Per 8-row tile: coalesced stage ->
// per-thread (row,slice) XOR accumulate vs LDS D[] -> one width-32 shfl
// reduce per row per tile. No atomics, no global combine, no per-element
// cross-lane ops.

#define GO_B    256
#define GO_N2   361
#define GO_M    3610
#define TBL     1024
#define BTHR    512
#define NBLK    8      // blocks per batch
#define ROWS_PB 46     // ceil(361/8)
#define TROWS   8      // rows per tile
#define STHR    256
#define NS      32     // column slices
#define CPS     12     // cols per slice (32*12 = 384 >= 361)

__global__ __launch_bounds__(STHR)
void scan_kernel(const int* __restrict__ cap,
                 const int* __restrict__ player,
                 const int* __restrict__ zpos,
                 uint32_t*  __restrict__ capx)      // [GO_B][GO_N2]
{
    __shared__ uint32_t Dl[GO_N2];                 // 1.4 KB
    __shared__ uint32_t tile[TROWS * GO_N2];       // 11.5 KB
    __shared__ uint32_t parts[TROWS][NS + 1];      // 1.1 KB (+1 pad)

    const int bq  = blockIdx.x;
    const int b   = bq >> 3;            // batch
    const int q   = bq & 7;             // row-range slice
    const int tid = threadIdx.x;
    const int p   = player[b];

    for (int j = tid; j < GO_N2; j += STHR)
        Dl[j] = (uint32_t)zpos[j * 3 + 0] ^ (uint32_t)zpos[j * 3 + 2 - p];
    __syncthreads();

    const int r0 = q * ROWS_PB;
    const int r1 = (r0 + ROWS_PB < GO_N2) ? (r0 + ROWS_PB) : GO_N2;
    const int* __restrict__ slab = cap + (size_t)b * GO_N2 * GO_N2;

    const int r  = tid & (TROWS - 1);   // row within tile
    const int s  = tid >> 3;            // slice 0..31
    const int j0 = s * CPS;

    for (int rt = r0; rt < r1; rt += TROWS) {
        const int nr  = (TROWS < r1 - rt) ? TROWS : (r1 - rt);
        const int nel = nr * GO_N2;
        const int* __restrict__ tsrc = slab + (size_t)rt * GO_N2;

        // coalesced stage: contiguous dword range of the slab
        for (int idx = tid; idx < nel; idx += STHR)
            tile[idx] = (uint32_t)tsrc[idx];
        __syncthreads();

        // per-thread accumulate over its 12-column slice (branch-free inner op)
        uint32_t acc = 0u;
        if (r < nr) {
            #pragma unroll
            for (int c = 0; c < CPS; ++c) {
                int j = j0 + c;
                if (j < GO_N2) {
                    uint32_t m = tile[r * GO_N2 + j];
                    acc ^= (m ? Dl[j] : 0u);
                }
            }
        }
        parts[r][s] = acc;
        __syncthreads();

        // reduce 32 slice-partials per row: 256 thr -> (row, k)
        {
            const int row = tid >> 5;
            const int k   = tid & 31;
            uint32_t v = parts[row][k];
            #pragma unroll
            for (int off = 16; off >= 1; off >>= 1)
                v ^= __shfl_xor(v, off, 32);
            if (k == 0 && rt + row < r1)
                capx[(size_t)b * GO_N2 + rt + row] = v;
        }
        __syncthreads();
    }
}

__global__ __launch_bounds__(BTHR)
void finalize_kernel(const int*      __restrict__ legal,
                     const int*      __restrict__ player,
                     const int*      __restrict__ zpos,
                     const int*      __restrict__ chash,
                     const int*      __restrict__ hist,
                     const int*      __restrict__ mcount,
                     const float*    __restrict__ logits,
                     const uint32_t* __restrict__ capx,
                     float*          __restrict__ out)
{
    __shared__ uint32_t thash[TBL];
    __shared__ int      tidx[TBL];
    __shared__ uint8_t  rep[GO_N2];
    __shared__ uint8_t  leg[GO_N2];

    const int b   = blockIdx.x;
    const int tid = threadIdx.x;
    const int p   = player[b];
    const uint32_t ch = (uint32_t)chash[b];

    for (int s = tid; s < TBL; s += BTHR) tidx[s] = -1;
    for (int i = tid; i < GO_N2; i += BTHR) {
        rep[i] = 0u;
        leg[i] = legal[(size_t)b * GO_N2 + i] != 0;
    }
    __syncthreads();

    for (int i = tid; i < GO_N2; i += BTHR) {
        uint32_t z0 = (uint32_t)zpos[i * 3 + 0];
        uint32_t zp = (uint32_t)zpos[i * 3 + 1 + p];
        uint32_t nh = ch ^ (z0 ^ zp) ^ capx[(size_t)b * GO_N2 + i];
        if (leg[i]) {
            uint32_t s = nh & (TBL - 1);
            while (true) {
                int prev = atomicCAS(&tidx[s], -1, i);
                if (prev == -1) { thash[s] = nh; break; }
                s = (s + 1) & (TBL - 1);
            }
        }
    }
    __syncthreads();

    const int mc = mcount[b];
    for (int m = tid; m < mc; m += BTHR) {
        uint32_t h = (uint32_t)hist[(size_t)b * GO_M + m];
        uint32_t s = h & (TBL - 1);
        while (tidx[s] != -1) {
            if (thash[s] == h) rep[tidx[s]] = 1u;
            s = (s + 1) & (TBL - 1);
        }
    }
    __syncthreads();

    for (int i = tid; i < GO_N2; i += BTHR) {
        bool keep = leg[i] && !rep[i];
        out[(size_t)b * GO_N2 + i] =
            keep ? logits[(size_t)b * GO_N2 + i] : -1.0e9f;
    }
}

extern "C" void kernel_launch(void* const* d_in, const int* in_sizes, int n_in,
                              void* d_out, int out_size, void* d_ws, size_t ws_size,
                              hipStream_t stream) {
    const int*   legal  = (const int*)d_in[0];
    const int*   cap    = (const int*)d_in[1];
    const int*   player = (const int*)d_in[2];
    const int*   zpos   = (const int*)d_in[3];
    const int*   chash  = (const int*)d_in[4];
    const int*   hist   = (const int*)d_in[5];
    const int*   mcount = (const int*)d_in[6];
    const float* logits = (const float*)d_in[7];
    float*       outp   = (float*)d_out;
    uint32_t*    capx   = (uint32_t*)d_ws;   // 256*361*4 B = 370 KB

    scan_kernel<<<GO_B * NBLK, STHR, 0, stream>>>(cap, player, zpos, capx);
    finalize_kernel<<<GO_B, BTHR, 0, stream>>>(legal, player, zpos, chash,
                                               hist, mcount, logits, capx, outp);
}